// Round 9
// baseline (283.944 us; speedup 1.0000x reference)
//
#include <hip/hip_runtime.h>
#include <hip/hip_bf16.h>

// REGATConv on MI355X — round 16. No-LDS direct-fragment GEMM, split across
// both sort phases; coalesced transposed scan.
//   ws: ftb bf16[N*256] | el[N*4] | er[N*4] | poffs[N+1] | ghist int[PB*256]
//       | lsg int[PB*256] | bb int[260] | mid int[E] | pk int[E]
//   K1 hist_gemm: blocks [0,PB) dst>>8 LDS hist -> ghist[blk][bin];
//      blocks [PB,PB+g1) direct-fragment MFMA GEMM tiles 0..g1.
//   K2 scan: 1 block, 256 thr (bin=tid): coalesced 8-unrolled column scan of
//      ghist -> lsg[blk][bin] (per-blk offsets) + block-scan -> bb[bin] bases.
//   K3 scat_gemm: blocks [0,PB) scatter via LDS cursors (bb+lsg) -> mid;
//      blocks [PB,..) GEMM tiles g1..782.
//   K4 bucket: per 256-node bucket LDS counting-group -> poffs + pk
//   K5 agg3: one wave per dst; 8-unrolled gather; fused-exp single pass.

#define NF 256
#define HD 256
#define NH 4
#define PB 256   // partition blocks

typedef __attribute__((ext_vector_type(8))) short short8;
typedef __attribute__((ext_vector_type(4))) float f32x4;

static __device__ __forceinline__ unsigned short f2bf(float f) {
  unsigned int u = __float_as_uint(f);
  u += 0x7FFFu + ((u >> 16) & 1u);   // RNE
  return (unsigned short)(u >> 16);
}
static __device__ __forceinline__ float bf2f(unsigned short s) {
  return __uint_as_float(((unsigned int)s) << 16);
}
static __device__ __forceinline__ unsigned pkbf(float a, float b) {
  __hip_bfloat162 h = __float22bfloat162_rn(make_float2(a, b));
  return *(unsigned*)&h;
}
static __device__ __forceinline__ float wcalc(float sum, float ew) {
  float x = sum * ew;
  x = (x >= 0.f) ? x : 0.2f * x;
  return __expf(x);
}
static __device__ __forceinline__ short8 cvt8(float4 x, float4 y) {
  union { short8 s; uint4 u; } cv;
  cv.u = make_uint4(pkbf(x.x, x.y), pkbf(x.z, x.w),
                    pkbf(y.x, y.y), pkbf(y.z, y.w));
  return cv.s;
}

// Direct-fragment GEMM tile: 64 rows x 256 cols, 4 waves (wave=head), no LDS.
// Fragment map (16x16x32): lane l: row/col = l&15, k = kc*32 + (l>>4)*8.
static __device__ __forceinline__ void gemm_tile_direct(
    const float* __restrict__ feat, const float* __restrict__ fc_w,
    const float* __restrict__ attn_l, const float* __restrict__ attn_r,
    unsigned short* __restrict__ ftb, float* __restrict__ el,
    float* __restrict__ er, int n, int row0, int tid) {
  int lane = tid & 63, w = tid >> 6;
  int rr = lane & 15, kq = lane >> 4;
  f32x4 acc[4][4];
#pragma unroll
  for (int i = 0; i < 4; ++i)
#pragma unroll
    for (int j = 0; j < 4; ++j) acc[i][j] = (f32x4){0.f, 0.f, 0.f, 0.f};

  const float* ap[4];
#pragma unroll
  for (int rt = 0; rt < 4; ++rt) {
    int arow = row0 + rt * 16 + rr; if (arow >= n) arow = n - 1;
    ap[rt] = feat + (size_t)arow * NF + kq * 8;
  }
  const float* bp[4];
#pragma unroll
  for (int ct = 0; ct < 4; ++ct) {
    int bcol = w * 64 + ct * 16 + rr;
    bp[ct] = fc_w + (size_t)bcol * NF + kq * 8;
  }

#pragma unroll 2
  for (int kc = 0; kc < 8; ++kc) {
    short8 afr[4], bfr[4];
#pragma unroll
    for (int rt = 0; rt < 4; ++rt) {
      float4 x = *(const float4*)(ap[rt] + kc * 32);
      float4 y = *(const float4*)(ap[rt] + kc * 32 + 4);
      afr[rt] = cvt8(x, y);
    }
#pragma unroll
    for (int ct = 0; ct < 4; ++ct) {
      float4 x = *(const float4*)(bp[ct] + kc * 32);
      float4 y = *(const float4*)(bp[ct] + kc * 32 + 4);
      bfr[ct] = cvt8(x, y);
    }
#pragma unroll
    for (int rt = 0; rt < 4; ++rt)
#pragma unroll
      for (int ct = 0; ct < 4; ++ct)
        acc[rt][ct] = __builtin_amdgcn_mfma_f32_16x16x32_bf16(
            afr[rt], bfr[ct], acc[rt][ct], 0, 0, 0);
  }

  // epilogue: wave w == head w. C/D map: col = lane&15, row = (lane>>4)*4 + r.
  int ln = lane & 15, lq = lane >> 4;
  float al4[4], ar4[4];
#pragma unroll
  for (int ct = 0; ct < 4; ++ct) {
    al4[ct] = attn_l[w * 64 + ct * 16 + ln];
    ar4[ct] = attn_r[w * 64 + ct * 16 + ln];
  }
#pragma unroll
  for (int rt = 0; rt < 4; ++rt) {
#pragma unroll
    for (int r = 0; r < 4; ++r) {
      float pl = 0.f, pr = 0.f;
#pragma unroll
      for (int ct = 0; ct < 4; ++ct) {
        float v = acc[rt][ct][r];
        pl += v * al4[ct]; pr += v * ar4[ct];
      }
#pragma unroll
      for (int off = 1; off <= 8; off <<= 1) {
        pl += __shfl_xor(pl, off);
        pr += __shfl_xor(pr, off);
      }
      int row = row0 + rt * 16 + lq * 4 + r;
      if (row < n) {
        if (ln == 0) { el[row * NH + w] = pl; er[row * NH + w] = pr; }
        unsigned short* fr = ftb + (size_t)row * HD + w * 64 + ln;
#pragma unroll
        for (int ct = 0; ct < 4; ++ct) fr[ct * 16] = f2bf(acc[rt][ct][r]);
      }
    }
  }
}

// K1: het-grid — hist blocks [0,hb) + gemm tiles [tile0, tile0 + gridDim-hb)
__global__ __launch_bounds__(256) void hist_gemm_k(
    const int* __restrict__ dst, int* __restrict__ ghist, int e, int epb, int hb,
    const float* __restrict__ feat, const float* __restrict__ fc_w,
    const float* __restrict__ attn_l, const float* __restrict__ attn_r,
    unsigned short* __restrict__ ftb, float* __restrict__ el,
    float* __restrict__ er, int n, int tile0) {
  int tid = threadIdx.x;
  if (blockIdx.x < hb) {
    __shared__ int bins[256];
    int blk = blockIdx.x;
    bins[tid] = 0;
    __syncthreads();
    int e0 = blk * epb, e1 = e0 + epb; if (e1 > e) e1 = e;
    for (int i = e0 + tid; i < e1; i += 256)
      atomicAdd(&bins[dst[i] >> 8], 1);
    __syncthreads();
    ghist[blk * 256 + tid] = bins[tid];   // [blk][bin], coalesced
    return;
  }
  gemm_tile_direct(feat, fc_w, attn_l, attn_r, ftb, el, er, n,
                   (tile0 + (int)blockIdx.x - hb) * 64, tid);
}

// K2: single block, 256 thr (tid = bin). Coalesced column scan over PB blocks.
__global__ __launch_bounds__(256) void scan_k(
    const int* __restrict__ ghist, int* __restrict__ lsg,
    int* __restrict__ bb, int nblk) {
  int tid = threadIdx.x;
  int run = 0;
  int i = 0;
  for (; i + 8 <= nblk; i += 8) {
    int v[8];
#pragma unroll
    for (int j = 0; j < 8; ++j) v[j] = ghist[(i + j) * 256 + tid];
#pragma unroll
    for (int j = 0; j < 8; ++j) { lsg[(i + j) * 256 + tid] = run; run += v[j]; }
  }
  for (; i < nblk; ++i) {
    int v = ghist[i * 256 + tid];
    lsg[i * 256 + tid] = run;
    run += v;
  }
  // block-wide exclusive scan of per-bin totals -> bb
  __shared__ int wt[4];
  int lane = tid & 63, wid = tid >> 6;
  int inc = run;
#pragma unroll
  for (int off = 1; off < 64; off <<= 1) {
    int t = __shfl_up(inc, off);
    if (lane >= off) inc += t;
  }
  if (lane == 63) wt[wid] = inc;
  __syncthreads();
  int base = 0;
  if (wid > 0) base += wt[0];
  if (wid > 1) base += wt[1];
  if (wid > 2) base += wt[2];
  bb[tid] = base + inc - run;
  if (tid == 255) bb[256] = base + inc;
}

// K3: het-grid — scatter blocks [0,sb) + gemm tiles [tile0, ...)
__global__ __launch_bounds__(256) void scat_gemm_k(
    const int* __restrict__ src, const int* __restrict__ dst,
    const int* __restrict__ efeats, const int* __restrict__ lsg,
    const int* __restrict__ bb, int* __restrict__ mid, int e, int epb, int sb,
    const float* __restrict__ feat, const float* __restrict__ fc_w,
    const float* __restrict__ attn_l, const float* __restrict__ attn_r,
    unsigned short* __restrict__ ftb, float* __restrict__ el,
    float* __restrict__ er, int n, int tile0) {
  int tid = threadIdx.x;
  if (blockIdx.x < sb) {
    __shared__ int cur[256];
    int blk = blockIdx.x;
    cur[tid] = bb[tid] + lsg[blk * 256 + tid];
    __syncthreads();
    int e0 = blk * epb, e1 = e0 + epb; if (e1 > e) e1 = e;
    for (int i = e0 + tid; i < e1; i += 256) {
      int d = dst[i];
      int pos = atomicAdd(&cur[d >> 8], 1);
      mid[pos] = src[i] | ((efeats[i] - 1) << 17) | ((d & 255) << 20);
    }
    return;
  }
  gemm_tile_direct(feat, fc_w, attn_l, attn_r, ftb, el, er, n,
                   (tile0 + (int)blockIdx.x - sb) * 64, tid);
}

// K4: per-bucket (256 nodes) LDS counting-group: poffs + dst-grouped pk
__global__ __launch_bounds__(256) void bucket_k(
    const int* __restrict__ mid, const int* __restrict__ bb,
    int* __restrict__ poffs, int* __restrict__ pk, int nN) {
  __shared__ int cnt[256];
  __shared__ int cur[256];
  int tid = threadIdx.x, b = blockIdx.x;
  int bb0 = bb[b];
  int bb1 = bb[b + 1];
  cnt[tid] = 0;
  __syncthreads();
  for (int i = bb0 + tid; i < bb1; i += 256)
    atomicAdd(&cnt[(mid[i] >> 20) & 255], 1);
  __syncthreads();
  if (tid < 64) {
    int carry = 0;
#pragma unroll
    for (int c = 0; c < 4; ++c) {
      int v = cnt[c * 64 + tid];
      int inc = v;
#pragma unroll
      for (int off = 1; off < 64; off <<= 1) {
        int t2 = __shfl_up(inc, off);
        if (tid >= off) inc += t2;
      }
      cur[c * 64 + tid] = inc - v + carry;
      carry += __shfl(inc, 63);
    }
  }
  __syncthreads();
  int node = b * 256 + tid;
  int g = bb0 + cur[tid];
  if (node <= nN) poffs[node] = g;
  cur[tid] = g;
  __syncthreads();
  for (int i = bb0 + tid; i < bb1; i += 256) {
    int v = mid[i];
    int pos = atomicAdd(&cur[(v >> 20) & 255], 1);
    pk[pos] = v & 0xFFFFF;
  }
}

// K5: one wave per dst node; lane owns output cols lane*4..lane*4+3 (head
// hl=lane>>4). Single pass: w=exp(leaky((el+er)*ew)) inline; scale by 1/ss.
__global__ __launch_bounds__(256) void agg3_k(
    const unsigned short* __restrict__ ftb, const int* __restrict__ pk,
    const float* __restrict__ el, const float* __restrict__ er,
    const float* __restrict__ ewt, const int* __restrict__ offs,
    float* __restrict__ out, int n) {
  __shared__ float ew_s[32];
  if (threadIdx.x < 32) {
    float v = ewt[threadIdx.x] * 100.0f;
    ew_s[threadIdx.x] = (v >= 0.f) ? v : 0.01f * v;
  }
  __syncthreads();
  int node = blockIdx.x * 4 + (threadIdx.x >> 6);
  int lane = threadIdx.x & 63;
  if (node >= n) return;
  int start = offs[node];
  int deg = offs[node + 1] - start;
  float o0 = 0.f, o1 = 0.f, o2 = 0.f, o3 = 0.f;
  if (deg > 0) {
    int hl = lane >> 4;
    float er_h = er[(size_t)node * NH + hl];
    const unsigned short* fb = ftb + (size_t)lane * 4;
    const float* elh = el + hl;
    const int* pg = pk + start;
    float ss = 0.f;
    int i = 0;
    for (; i + 8 <= deg; i += 8) {
      int4 pa = *(const int4*)(pg + i);
      int4 pb = *(const int4*)(pg + i + 4);
      int sA = pa.x & 0x1FFFF, tA = pa.x >> 17;
      int sB = pa.y & 0x1FFFF, tB = pa.y >> 17;
      int sC = pa.z & 0x1FFFF, tC = pa.z >> 17;
      int sD = pa.w & 0x1FFFF, tD = pa.w >> 17;
      int sE = pb.x & 0x1FFFF, tE = pb.x >> 17;
      int sF = pb.y & 0x1FFFF, tF = pb.y >> 17;
      int sG = pb.z & 0x1FFFF, tG = pb.z >> 17;
      int sH = pb.w & 0x1FFFF, tH = pb.w >> 17;
      float eA = elh[sA * NH], eB = elh[sB * NH], eC = elh[sC * NH], eD = elh[sD * NH];
      float eE = elh[sE * NH], eF = elh[sF * NH], eG = elh[sG * NH], eH = elh[sH * NH];
      ushort4 fA = *(const ushort4*)(fb + (size_t)sA * HD);
      ushort4 fB = *(const ushort4*)(fb + (size_t)sB * HD);
      ushort4 fC = *(const ushort4*)(fb + (size_t)sC * HD);
      ushort4 fD = *(const ushort4*)(fb + (size_t)sD * HD);
      ushort4 fE = *(const ushort4*)(fb + (size_t)sE * HD);
      ushort4 fF = *(const ushort4*)(fb + (size_t)sF * HD);
      ushort4 fG = *(const ushort4*)(fb + (size_t)sG * HD);
      ushort4 fH = *(const ushort4*)(fb + (size_t)sH * HD);
      float wA = wcalc(eA + er_h, ew_s[tA * NH + hl]);
      float wB = wcalc(eB + er_h, ew_s[tB * NH + hl]);
      float wC = wcalc(eC + er_h, ew_s[tC * NH + hl]);
      float wD = wcalc(eD + er_h, ew_s[tD * NH + hl]);
      float wE = wcalc(eE + er_h, ew_s[tE * NH + hl]);
      float wF = wcalc(eF + er_h, ew_s[tF * NH + hl]);
      float wG = wcalc(eG + er_h, ew_s[tG * NH + hl]);
      float wH = wcalc(eH + er_h, ew_s[tH * NH + hl]);
      ss += ((wA + wB) + (wC + wD)) + ((wE + wF) + (wG + wH));
      o0 = fmaf(wA, bf2f(fA.x), o0); o1 = fmaf(wA, bf2f(fA.y), o1);
      o2 = fmaf(wA, bf2f(fA.z), o2); o3 = fmaf(wA, bf2f(fA.w), o3);
      o0 = fmaf(wB, bf2f(fB.x), o0); o1 = fmaf(wB, bf2f(fB.y), o1);
      o2 = fmaf(wB, bf2f(fB.z), o2); o3 = fmaf(wB, bf2f(fB.w), o3);
      o0 = fmaf(wC, bf2f(fC.x), o0); o1 = fmaf(wC, bf2f(fC.y), o1);
      o2 = fmaf(wC, bf2f(fC.z), o2); o3 = fmaf(wC, bf2f(fC.w), o3);
      o0 = fmaf(wD, bf2f(fD.x), o0); o1 = fmaf(wD, bf2f(fD.y), o1);
      o2 = fmaf(wD, bf2f(fD.z), o2); o3 = fmaf(wD, bf2f(fD.w), o3);
      o0 = fmaf(wE, bf2f(fE.x), o0); o1 = fmaf(wE, bf2f(fE.y), o1);
      o2 = fmaf(wE, bf2f(fE.z), o2); o3 = fmaf(wE, bf2f(fE.w), o3);
      o0 = fmaf(wF, bf2f(fF.x), o0); o1 = fmaf(wF, bf2f(fF.y), o1);
      o2 = fmaf(wF, bf2f(fF.z), o2); o3 = fmaf(wF, bf2f(fF.w), o3);
      o0 = fmaf(wG, bf2f(fG.x), o0); o1 = fmaf(wG, bf2f(fG.y), o1);
      o2 = fmaf(wG, bf2f(fG.z), o2); o3 = fmaf(wG, bf2f(fG.w), o3);
      o0 = fmaf(wH, bf2f(fH.x), o0); o1 = fmaf(wH, bf2f(fH.y), o1);
      o2 = fmaf(wH, bf2f(fH.z), o2); o3 = fmaf(wH, bf2f(fH.w), o3);
    }
    for (; i < deg; ++i) {
      int pv = pg[i];
      int sA = pv & 0x1FFFF, tA = pv >> 17;
      float eA = elh[sA * NH];
      ushort4 fA = *(const ushort4*)(fb + (size_t)sA * HD);
      float wA = wcalc(eA + er_h, ew_s[tA * NH + hl]);
      ss += wA;
      o0 = fmaf(wA, bf2f(fA.x), o0); o1 = fmaf(wA, bf2f(fA.y), o1);
      o2 = fmaf(wA, bf2f(fA.z), o2); o3 = fmaf(wA, bf2f(fA.w), o3);
    }
    float rs = 1.0f / ss;
    o0 *= rs; o1 *= rs; o2 *= rs; o3 *= rs;
  }
  *(float4*)(out + (size_t)node * HD + lane * 4) = make_float4(o0, o1, o2, o3);
}

extern "C" void kernel_launch(void* const* d_in, const int* in_sizes, int n_in,
                              void* d_out, int out_size, void* d_ws, size_t ws_size,
                              hipStream_t stream) {
  const float* feat   = (const float*)d_in[0];
  const int*   src    = (const int*)d_in[1];
  const int*   dst    = (const int*)d_in[2];
  const int*   efeats = (const int*)d_in[3];
  const float* fc_w   = (const float*)d_in[4];
  const float* attn_l = (const float*)d_in[5];
  const float* attn_r = (const float*)d_in[6];
  const float* ewt    = (const float*)d_in[7];
  float* out = (float*)d_out;

  int N = in_sizes[0] / NF;   // 50000
  int E = in_sizes[1];        // 800000

  char* ws = (char*)d_ws;
  size_t off = 0;
  unsigned short* ftb = (unsigned short*)(ws + off); off += (size_t)N * HD * 2;   // 25.6 MB
  float* el  = (float*)(ws + off);  off += (size_t)N * NH * 4;
  float* er  = (float*)(ws + off);  off += (size_t)N * NH * 4;
  int* poffs = (int*)(ws + off);    off += ((size_t)N + 16) * 4;
  int* ghist = (int*)(ws + off);    off += (size_t)PB * 256 * 4;                  // 256 KB
  int* lsg   = (int*)(ws + off);    off += (size_t)PB * 256 * 4;                  // 256 KB
  int* bb    = (int*)(ws + off);    off += 260 * 4;
  int* mid   = (int*)(ws + off);    off += (size_t)E * 4;                          // 3.2 MB
  int* pk    = (int*)(ws + off);    off += (size_t)E * 4;                          // 3.2 MB

  int gb = (N + 63) / 64;            // 782 GEMM tiles
  int g1 = gb / 2;                   // tiles in phase 1
  int g2 = gb - g1;                  // tiles in phase 2
  int epb = (E + PB - 1) / PB;       // 3125 edges per partition block
  int nbuck = (N + 255) >> 8;        // 196 buckets

  hist_gemm_k<<<PB + g1, 256, 0, stream>>>(dst, ghist, E, epb, PB,
                                           feat, fc_w, attn_l, attn_r,
                                           ftb, el, er, N, 0);
  scan_k<<<1, 256, 0, stream>>>(ghist, lsg, bb, PB);
  scat_gemm_k<<<PB + g2, 256, 0, stream>>>(src, dst, efeats, lsg, bb, mid,
                                           E, epb, PB,
                                           feat, fc_w, attn_l, attn_r,
                                           ftb, el, er, N, g1);
  bucket_k<<<nbuck, 256, 0, stream>>>(mid, bb, poffs, pk, N);
  agg3_k<<<(N + 3) / 4, 256, 0, stream>>>(ftb, pk, el, er, ewt, poffs, out, N);
}

// Round 10
// 249.935 us; speedup vs baseline: 1.1361x; 1.1361x over previous
//
#include <hip/hip_runtime.h>
#include <hip/hip_bf16.h>

// REGATConv on MI355X — round 17. R15 LDS-GEMM split across BOTH sort phases;
// R16 coalesced transposed scan; no fcb buffer (B staged from fp32 directly).
//   ws: ftb bf16[N*256] | el[N*4] | er[N*4] | poffs[N+1] | ghist int[PB*256]
//       | lsg int[PB*256] | bb int[260] | mid int[E] | pk int[E]
//   K1 hist_gemm: blocks [0,PB) LDS 256-bin hist of dst>>8 -> ghist[blk][bin]
//      (coalesced); blocks [PB,PB+g1) LDS MFMA GEMM tiles [0,g1).
//   K2 scan: 1 block x 256 thr (tid=bin): coalesced column scan of ghist ->
//      lsg[blk][bin] + per-bin bases bb[257].
//   K3 scat_gemm: blocks [0,PB) scatter via LDS cursors (bb+lsg) -> mid;
//      blocks [PB,..) GEMM tiles [g1,782).
//   K4 bucket: per 256-node bucket LDS counting-group -> poffs + pk
//   K5 agg3: one wave per dst; 8-unrolled gather; fused-exp single pass.

#define NF 256
#define HD 256
#define NH 4
#define PB 256   // partition blocks

typedef __attribute__((ext_vector_type(8))) short short8;
typedef __attribute__((ext_vector_type(4))) float f32x4;

static __device__ __forceinline__ unsigned short f2bf(float f) {
  unsigned int u = __float_as_uint(f);
  u += 0x7FFFu + ((u >> 16) & 1u);   // RNE
  return (unsigned short)(u >> 16);
}
static __device__ __forceinline__ float bf2f(unsigned short s) {
  return __uint_as_float(((unsigned int)s) << 16);
}
static __device__ __forceinline__ unsigned pkbf(float a, float b) {
  __hip_bfloat162 h = __float22bfloat162_rn(make_float2(a, b));
  return *(unsigned*)&h;
}
static __device__ __forceinline__ float wcalc(float sum, float ew) {
  float x = sum * ew;
  x = (x >= 0.f) ? x : 0.2f * x;
  return __expf(x);
}
static __device__ __forceinline__ short8 cvt8(float4 x, float4 y) {
  union { short8 s; uint4 u; } cv;
  cv.u = make_uint4(pkbf(x.x, x.y), pkbf(x.z, x.w),
                    pkbf(y.x, y.y), pkbf(y.z, y.w));
  return cv.s;
}

// LDS MFMA GEMM tile: 64 rows x 256 cols, 4 waves (wave=head), BK=64.
// A staged from feat fp32; B staged from fc_w fp32 (L2-resident, converted
// in-register). Same LDS layout as rounds 13/15 (verified).
static __device__ __forceinline__ void gemm_tile(
    const float* __restrict__ feat, const float* __restrict__ fc_w,
    const float* __restrict__ attn_l, const float* __restrict__ attn_r,
    unsigned short* __restrict__ ftb, float* __restrict__ el,
    float* __restrict__ er, int n, int row0, int tid,
    short* aF, short* bF) {
  int lane = tid & 63, w = tid >> 6;

  f32x4 acc[4][4];
#pragma unroll
  for (int i = 0; i < 4; ++i)
#pragma unroll
    for (int j = 0; j < 4; ++j) acc[i][j] = (f32x4){0.f, 0.f, 0.f, 0.f};

  int ar = tid >> 2, ak = (tid & 3) << 4;
  int arow = row0 + ar; if (arow >= n) arow = n - 1;
  const float* ap = feat + (size_t)arow * NF + ak;
  int am = ar & 15, art = ar >> 4;
  int s0 = ak >> 5, q0 = (ak >> 3) & 3;
  int s1 = (ak + 8) >> 5, q1 = ((ak + 8) >> 3) & 3;
  short* aw0 = &aF[(((art * 2 + s0) * 64) + q0 * 16 + am) * 8];
  short* aw1 = &aF[(((art * 2 + s1) * 64) + q1 * 16 + am) * 8];

  const float* bp = fc_w + (size_t)tid * NF;   // fp32 row of output col `tid`
  int bn = tid & 15, bcg = tid >> 4;

  for (int k0 = 0; k0 < NF; k0 += 64) {
    float4 f0 = *(const float4*)(ap + k0);
    float4 f1 = *(const float4*)(ap + k0 + 4);
    float4 f2 = *(const float4*)(ap + k0 + 8);
    float4 f3 = *(const float4*)(ap + k0 + 12);
    uint4 oa = make_uint4(pkbf(f0.x, f0.y), pkbf(f0.z, f0.w),
                          pkbf(f1.x, f1.y), pkbf(f1.z, f1.w));
    uint4 ob = make_uint4(pkbf(f2.x, f2.y), pkbf(f2.z, f2.w),
                          pkbf(f3.x, f3.y), pkbf(f3.z, f3.w));
    *(uint4*)aw0 = oa;
    *(uint4*)aw1 = ob;
#pragma unroll
    for (int o8 = 0; o8 < 8; ++o8) {
      float4 bx = *(const float4*)(bp + k0 + o8 * 8);
      float4 by = *(const float4*)(bp + k0 + o8 * 8 + 4);
      short8 bv = cvt8(bx, by);
      int bs = o8 >> 2, bq = o8 & 3;
      *(short8*)&bF[(((bcg * 2 + bs) * 64) + bq * 16 + bn) * 8] = bv;
    }
    __syncthreads();
#pragma unroll
    for (int s = 0; s < 2; ++s) {
      short8 af[4], bfr[4];
#pragma unroll
      for (int rt = 0; rt < 4; ++rt)
        af[rt] = *(const short8*)&aF[(((rt * 2 + s) * 64) + lane) * 8];
#pragma unroll
      for (int ct = 0; ct < 4; ++ct)
        bfr[ct] = *(const short8*)&bF[((((w * 4 + ct) * 2 + s) * 64) + lane) * 8];
#pragma unroll
      for (int rt = 0; rt < 4; ++rt)
#pragma unroll
        for (int ct = 0; ct < 4; ++ct)
          acc[rt][ct] = __builtin_amdgcn_mfma_f32_16x16x32_bf16(
              af[rt], bfr[ct], acc[rt][ct], 0, 0, 0);
    }
    __syncthreads();
  }

  // epilogue: wave w == head w. C/D map: col = lane&15, row = (lane>>4)*4 + r.
  int ln = lane & 15, lq = lane >> 4;
  float al4[4], ar4[4];
#pragma unroll
  for (int ct = 0; ct < 4; ++ct) {
    al4[ct] = attn_l[w * 64 + ct * 16 + ln];
    ar4[ct] = attn_r[w * 64 + ct * 16 + ln];
  }
#pragma unroll
  for (int rt = 0; rt < 4; ++rt) {
#pragma unroll
    for (int r = 0; r < 4; ++r) {
      float pl = 0.f, pr = 0.f;
#pragma unroll
      for (int ct = 0; ct < 4; ++ct) {
        float v = acc[rt][ct][r];
        pl += v * al4[ct]; pr += v * ar4[ct];
      }
#pragma unroll
      for (int off = 1; off <= 8; off <<= 1) {
        pl += __shfl_xor(pl, off);
        pr += __shfl_xor(pr, off);
      }
      int row = row0 + rt * 16 + lq * 4 + r;
      if (row < n) {
        if (ln == 0) { el[row * NH + w] = pl; er[row * NH + w] = pr; }
        unsigned short* fr = ftb + (size_t)row * HD + w * 64 + ln;
#pragma unroll
        for (int ct = 0; ct < 4; ++ct) fr[ct * 16] = f2bf(acc[rt][ct][r]);
      }
    }
  }
}

// K1: het-grid — hist blocks [0,hb) + gemm tiles [0, gridDim-hb)
__global__ __launch_bounds__(256) void hist_gemm_k(
    const int* __restrict__ dst, int* __restrict__ ghist, int e, int epb, int hb,
    const float* __restrict__ feat, const float* __restrict__ fc_w,
    const float* __restrict__ attn_l, const float* __restrict__ attn_r,
    unsigned short* __restrict__ ftb, float* __restrict__ el,
    float* __restrict__ er, int n) {
  __shared__ short aF[4 * 2 * 64 * 8];    // 8 KB (hist reuses as bins)
  __shared__ short bF[16 * 2 * 64 * 8];   // 32 KB
  int tid = threadIdx.x;
  if (blockIdx.x < hb) {
    int* bins = (int*)aF;
    int blk = blockIdx.x;
    bins[tid] = 0;
    __syncthreads();
    int e0 = blk * epb, e1 = e0 + epb; if (e1 > e) e1 = e;
    for (int i = e0 + tid; i < e1; i += 256)
      atomicAdd(&bins[dst[i] >> 8], 1);
    __syncthreads();
    ghist[blk * 256 + tid] = bins[tid];   // [blk][bin], coalesced
    return;
  }
  gemm_tile(feat, fc_w, attn_l, attn_r, ftb, el, er, n,
            ((int)blockIdx.x - hb) * 64, tid, aF, bF);
}

// K2: single block, 256 thr (tid = bin). Coalesced column scan over PB blocks.
__global__ __launch_bounds__(256) void scan_k(
    const int* __restrict__ ghist, int* __restrict__ lsg,
    int* __restrict__ bb, int nblk) {
  int tid = threadIdx.x;
  int run = 0;
  int i = 0;
  for (; i + 8 <= nblk; i += 8) {
    int v[8];
#pragma unroll
    for (int j = 0; j < 8; ++j) v[j] = ghist[(i + j) * 256 + tid];
#pragma unroll
    for (int j = 0; j < 8; ++j) { lsg[(i + j) * 256 + tid] = run; run += v[j]; }
  }
  for (; i < nblk; ++i) {
    int v = ghist[i * 256 + tid];
    lsg[i * 256 + tid] = run;
    run += v;
  }
  // block-wide exclusive scan of per-bin totals -> bb
  __shared__ int wt[4];
  int lane = tid & 63, wid = tid >> 6;
  int inc = run;
#pragma unroll
  for (int off = 1; off < 64; off <<= 1) {
    int t = __shfl_up(inc, off);
    if (lane >= off) inc += t;
  }
  if (lane == 63) wt[wid] = inc;
  __syncthreads();
  int base = 0;
  if (wid > 0) base += wt[0];
  if (wid > 1) base += wt[1];
  if (wid > 2) base += wt[2];
  bb[tid] = base + inc - run;
  if (tid == 255) bb[256] = base + inc;
}

// K3: het-grid — scatter blocks [0,sb) + gemm tiles [tile0, ...)
__global__ __launch_bounds__(256) void scat_gemm_k(
    const int* __restrict__ src, const int* __restrict__ dst,
    const int* __restrict__ efeats, const int* __restrict__ lsg,
    const int* __restrict__ bb, int* __restrict__ mid, int e, int epb, int sb,
    const float* __restrict__ feat, const float* __restrict__ fc_w,
    const float* __restrict__ attn_l, const float* __restrict__ attn_r,
    unsigned short* __restrict__ ftb, float* __restrict__ el,
    float* __restrict__ er, int n, int tile0) {
  __shared__ short aF[4 * 2 * 64 * 8];    // 8 KB (scatter reuses as cursors)
  __shared__ short bF[16 * 2 * 64 * 8];   // 32 KB
  int tid = threadIdx.x;
  if (blockIdx.x < sb) {
    int* cur = (int*)aF;
    int blk = blockIdx.x;
    cur[tid] = bb[tid] + lsg[blk * 256 + tid];
    __syncthreads();
    int e0 = blk * epb, e1 = e0 + epb; if (e1 > e) e1 = e;
    for (int i = e0 + tid; i < e1; i += 256) {
      int d = dst[i];
      int pos = atomicAdd(&cur[d >> 8], 1);
      mid[pos] = src[i] | ((efeats[i] - 1) << 17) | ((d & 255) << 20);
    }
    return;
  }
  gemm_tile(feat, fc_w, attn_l, attn_r, ftb, el, er, n,
            (tile0 + (int)blockIdx.x - sb) * 64, tid, aF, bF);
}

// K4: per-bucket (256 nodes) LDS counting-group: poffs + dst-grouped pk
__global__ __launch_bounds__(256) void bucket_k(
    const int* __restrict__ mid, const int* __restrict__ bb,
    int* __restrict__ poffs, int* __restrict__ pk, int nN) {
  __shared__ int cnt[256];
  __shared__ int cur[256];
  int tid = threadIdx.x, b = blockIdx.x;
  int bb0 = bb[b];
  int bb1 = bb[b + 1];
  cnt[tid] = 0;
  __syncthreads();
  for (int i = bb0 + tid; i < bb1; i += 256)
    atomicAdd(&cnt[(mid[i] >> 20) & 255], 1);
  __syncthreads();
  if (tid < 64) {
    int carry = 0;
#pragma unroll
    for (int c = 0; c < 4; ++c) {
      int v = cnt[c * 64 + tid];
      int inc = v;
#pragma unroll
      for (int off = 1; off < 64; off <<= 1) {
        int t2 = __shfl_up(inc, off);
        if (tid >= off) inc += t2;
      }
      cur[c * 64 + tid] = inc - v + carry;
      carry += __shfl(inc, 63);
    }
  }
  __syncthreads();
  int node = b * 256 + tid;
  int g = bb0 + cur[tid];
  if (node <= nN) poffs[node] = g;
  cur[tid] = g;
  __syncthreads();
  for (int i = bb0 + tid; i < bb1; i += 256) {
    int v = mid[i];
    int pos = atomicAdd(&cur[(v >> 20) & 255], 1);
    pk[pos] = v & 0xFFFFF;
  }
}

// K5: one wave per dst node; lane owns output cols lane*4..lane*4+3 (head
// hl=lane>>4). Single pass: w=exp(leaky((el+er)*ew)) inline; scale by 1/ss.
__global__ __launch_bounds__(256) void agg3_k(
    const unsigned short* __restrict__ ftb, const int* __restrict__ pk,
    const float* __restrict__ el, const float* __restrict__ er,
    const float* __restrict__ ewt, const int* __restrict__ offs,
    float* __restrict__ out, int n) {
  __shared__ float ew_s[32];
  if (threadIdx.x < 32) {
    float v = ewt[threadIdx.x] * 100.0f;
    ew_s[threadIdx.x] = (v >= 0.f) ? v : 0.01f * v;
  }
  __syncthreads();
  int node = blockIdx.x * 4 + (threadIdx.x >> 6);
  int lane = threadIdx.x & 63;
  if (node >= n) return;
  int start = offs[node];
  int deg = offs[node + 1] - start;
  float o0 = 0.f, o1 = 0.f, o2 = 0.f, o3 = 0.f;
  if (deg > 0) {
    int hl = lane >> 4;
    float er_h = er[(size_t)node * NH + hl];
    const unsigned short* fb = ftb + (size_t)lane * 4;
    const float* elh = el + hl;
    const int* pg = pk + start;
    float ss = 0.f;
    int i = 0;
    for (; i + 8 <= deg; i += 8) {
      int4 pa = *(const int4*)(pg + i);
      int4 pb = *(const int4*)(pg + i + 4);
      int sA = pa.x & 0x1FFFF, tA = pa.x >> 17;
      int sB = pa.y & 0x1FFFF, tB = pa.y >> 17;
      int sC = pa.z & 0x1FFFF, tC = pa.z >> 17;
      int sD = pa.w & 0x1FFFF, tD = pa.w >> 17;
      int sE = pb.x & 0x1FFFF, tE = pb.x >> 17;
      int sF = pb.y & 0x1FFFF, tF = pb.y >> 17;
      int sG = pb.z & 0x1FFFF, tG = pb.z >> 17;
      int sH = pb.w & 0x1FFFF, tH = pb.w >> 17;
      float eA = elh[sA * NH], eB = elh[sB * NH], eC = elh[sC * NH], eD = elh[sD * NH];
      float eE = elh[sE * NH], eF = elh[sF * NH], eG = elh[sG * NH], eH = elh[sH * NH];
      ushort4 fA = *(const ushort4*)(fb + (size_t)sA * HD);
      ushort4 fB = *(const ushort4*)(fb + (size_t)sB * HD);
      ushort4 fC = *(const ushort4*)(fb + (size_t)sC * HD);
      ushort4 fD = *(const ushort4*)(fb + (size_t)sD * HD);
      ushort4 fE = *(const ushort4*)(fb + (size_t)sE * HD);
      ushort4 fF = *(const ushort4*)(fb + (size_t)sF * HD);
      ushort4 fG = *(const ushort4*)(fb + (size_t)sG * HD);
      ushort4 fH = *(const ushort4*)(fb + (size_t)sH * HD);
      float wA = wcalc(eA + er_h, ew_s[tA * NH + hl]);
      float wB = wcalc(eB + er_h, ew_s[tB * NH + hl]);
      float wC = wcalc(eC + er_h, ew_s[tC * NH + hl]);
      float wD = wcalc(eD + er_h, ew_s[tD * NH + hl]);
      float wE = wcalc(eE + er_h, ew_s[tE * NH + hl]);
      float wF = wcalc(eF + er_h, ew_s[tF * NH + hl]);
      float wG = wcalc(eG + er_h, ew_s[tG * NH + hl]);
      float wH = wcalc(eH + er_h, ew_s[tH * NH + hl]);
      ss += ((wA + wB) + (wC + wD)) + ((wE + wF) + (wG + wH));
      o0 = fmaf(wA, bf2f(fA.x), o0); o1 = fmaf(wA, bf2f(fA.y), o1);
      o2 = fmaf(wA, bf2f(fA.z), o2); o3 = fmaf(wA, bf2f(fA.w), o3);
      o0 = fmaf(wB, bf2f(fB.x), o0); o1 = fmaf(wB, bf2f(fB.y), o1);
      o2 = fmaf(wB, bf2f(fB.z), o2); o3 = fmaf(wB, bf2f(fB.w), o3);
      o0 = fmaf(wC, bf2f(fC.x), o0); o1 = fmaf(wC, bf2f(fC.y), o1);
      o2 = fmaf(wC, bf2f(fC.z), o2); o3 = fmaf(wC, bf2f(fC.w), o3);
      o0 = fmaf(wD, bf2f(fD.x), o0); o1 = fmaf(wD, bf2f(fD.y), o1);
      o2 = fmaf(wD, bf2f(fD.z), o2); o3 = fmaf(wD, bf2f(fD.w), o3);
      o0 = fmaf(wE, bf2f(fE.x), o0); o1 = fmaf(wE, bf2f(fE.y), o1);
      o2 = fmaf(wE, bf2f(fE.z), o2); o3 = fmaf(wE, bf2f(fE.w), o3);
      o0 = fmaf(wF, bf2f(fF.x), o0); o1 = fmaf(wF, bf2f(fF.y), o1);
      o2 = fmaf(wF, bf2f(fF.z), o2); o3 = fmaf(wF, bf2f(fF.w), o3);
      o0 = fmaf(wG, bf2f(fG.x), o0); o1 = fmaf(wG, bf2f(fG.y), o1);
      o2 = fmaf(wG, bf2f(fG.z), o2); o3 = fmaf(wG, bf2f(fG.w), o3);
      o0 = fmaf(wH, bf2f(fH.x), o0); o1 = fmaf(wH, bf2f(fH.y), o1);
      o2 = fmaf(wH, bf2f(fH.z), o2); o3 = fmaf(wH, bf2f(fH.w), o3);
    }
    for (; i < deg; ++i) {
      int pv = pg[i];
      int sA = pv & 0x1FFFF, tA = pv >> 17;
      float eA = elh[sA * NH];
      ushort4 fA = *(const ushort4*)(fb + (size_t)sA * HD);
      float wA = wcalc(eA + er_h, ew_s[tA * NH + hl]);
      ss += wA;
      o0 = fmaf(wA, bf2f(fA.x), o0); o1 = fmaf(wA, bf2f(fA.y), o1);
      o2 = fmaf(wA, bf2f(fA.z), o2); o3 = fmaf(wA, bf2f(fA.w), o3);
    }
    float rs = 1.0f / ss;
    o0 *= rs; o1 *= rs; o2 *= rs; o3 *= rs;
  }
  *(float4*)(out + (size_t)node * HD + lane * 4) = make_float4(o0, o1, o2, o3);
}

extern "C" void kernel_launch(void* const* d_in, const int* in_sizes, int n_in,
                              void* d_out, int out_size, void* d_ws, size_t ws_size,
                              hipStream_t stream) {
  const float* feat   = (const float*)d_in[0];
  const int*   src    = (const int*)d_in[1];
  const int*   dst    = (const int*)d_in[2];
  const int*   efeats = (const int*)d_in[3];
  const float* fc_w   = (const float*)d_in[4];
  const float* attn_l = (const float*)d_in[5];
  const float* attn_r = (const float*)d_in[6];
  const float* ewt    = (const float*)d_in[7];
  float* out = (float*)d_out;

  int N = in_sizes[0] / NF;   // 50000
  int E = in_sizes[1];        // 800000

  char* ws = (char*)d_ws;
  size_t off = 0;
  unsigned short* ftb = (unsigned short*)(ws + off); off += (size_t)N * HD * 2;   // 25.6 MB
  float* el  = (float*)(ws + off);  off += (size_t)N * NH * 4;
  float* er  = (float*)(ws + off);  off += (size_t)N * NH * 4;
  int* poffs = (int*)(ws + off);    off += ((size_t)N + 16) * 4;
  int* ghist = (int*)(ws + off);    off += (size_t)PB * 256 * 4;                  // 256 KB
  int* lsg   = (int*)(ws + off);    off += (size_t)PB * 256 * 4;                  // 256 KB
  int* bb    = (int*)(ws + off);    off += 260 * 4;
  int* mid   = (int*)(ws + off);    off += (size_t)E * 4;                          // 3.2 MB
  int* pk    = (int*)(ws + off);    off += (size_t)E * 4;                          // 3.2 MB

  int gb = (N + 63) / 64;            // 782 GEMM tiles
  int g1 = 430;                      // tiles overlapped with hist (lighter)
  int g2 = gb - g1;                  // 352 tiles overlapped with scatter
  int epb = (E + PB - 1) / PB;       // 3125 edges per partition block
  int nbuck = (N + 255) >> 8;        // 196 buckets

  hist_gemm_k<<<PB + g1, 256, 0, stream>>>(dst, ghist, E, epb, PB,
                                           feat, fc_w, attn_l, attn_r,
                                           ftb, el, er, N);
  scan_k<<<1, 256, 0, stream>>>(ghist, lsg, bb, PB);
  scat_gemm_k<<<PB + g2, 256, 0, stream>>>(src, dst, efeats, lsg, bb, mid,
                                           E, epb, PB,
                                           feat, fc_w, attn_l, attn_r,
                                           ftb, el, er, N, g1);
  bucket_k<<<nbuck, 256, 0, stream>>>(mid, bb, poffs, pk, N);
  agg3_k<<<(N + 3) / 4, 256, 0, stream>>>(ftb, pk, el, er, ewt, poffs, out, N);
}

// Round 11
// 249.711 us; speedup vs baseline: 1.1371x; 1.0009x over previous
//
#include <hip/hip_runtime.h>
#include <hip/hip_bf16.h>

// REGATConv on MI355X — round 18. GEMM v2: A double-buffered in LDS (16 KB),
// B direct from L2-resident fp32 fc_w (no bF stage), 1 barrier per k0.
//   ws: ftb bf16[N*256] | el[N*4] | er[N*4] | poffs[N+1] | ghist int[PB*256]
//       | lsg int[PB*256] | bb int[260] | mid int[E] | pk int[E]
//   K1 hist_gemm: blocks [0,PB) LDS 256-bin hist of dst>>8 -> ghist[blk][bin];
//      blocks [PB,PB+g1) GEMM v2 tiles [0,g1).
//   K2 scan: 1 block x 256 thr (tid=bin): coalesced column scan of ghist ->
//      lsg[blk][bin] + per-bin bases bb[257].
//   K3 scat_gemm: blocks [0,PB) scatter via LDS cursors (bb+lsg) -> mid;
//      blocks [PB,..) GEMM v2 tiles [g1,782).
//   K4 bucket: per 256-node bucket LDS counting-group -> poffs + pk
//   K5 agg3: one wave per dst; 8-unrolled gather; fused-exp single pass.

#define NF 256
#define HD 256
#define NH 4
#define PB 256   // partition blocks

typedef __attribute__((ext_vector_type(8))) short short8;
typedef __attribute__((ext_vector_type(4))) float f32x4;

static __device__ __forceinline__ unsigned short f2bf(float f) {
  unsigned int u = __float_as_uint(f);
  u += 0x7FFFu + ((u >> 16) & 1u);   // RNE
  return (unsigned short)(u >> 16);
}
static __device__ __forceinline__ float bf2f(unsigned short s) {
  return __uint_as_float(((unsigned int)s) << 16);
}
static __device__ __forceinline__ unsigned pkbf(float a, float b) {
  __hip_bfloat162 h = __float22bfloat162_rn(make_float2(a, b));
  return *(unsigned*)&h;
}
static __device__ __forceinline__ float wcalc(float sum, float ew) {
  float x = sum * ew;
  x = (x >= 0.f) ? x : 0.2f * x;
  return __expf(x);
}
static __device__ __forceinline__ short8 cvt8(float4 x, float4 y) {
  union { short8 s; uint4 u; } cv;
  cv.u = make_uint4(pkbf(x.x, x.y), pkbf(x.z, x.w),
                    pkbf(y.x, y.y), pkbf(y.z, y.w));
  return cv.s;
}

// GEMM v2 tile: 64 rows x 256 cols, 4 waves (wave=head), BK=64.
// A: staged fp32->bf16 into double-buffered LDS (2 x 8 KB), 1 barrier/k0.
// B: fragments read DIRECT from fp32 fc_w (L2-resident), cvt in-register —
//    fragment map verified in round 16 (lane l: col l&15, k=(l>>4)*8 + 32s).
static __device__ __forceinline__ void gemm_tile(
    const float* __restrict__ feat, const float* __restrict__ fc_w,
    const float* __restrict__ attn_l, const float* __restrict__ attn_r,
    unsigned short* __restrict__ ftb, float* __restrict__ el,
    float* __restrict__ er, int n, int row0, int tid, short* aF) {
  int lane = tid & 63, w = tid >> 6;
  int rr = lane & 15, kq = lane >> 4;

  f32x4 acc[4][4];
#pragma unroll
  for (int i = 0; i < 4; ++i)
#pragma unroll
    for (int j = 0; j < 4; ++j) acc[i][j] = (f32x4){0.f, 0.f, 0.f, 0.f};

  // A staging addresses (same layout as rounds 13-17, verified)
  int ar = tid >> 2, ak = (tid & 3) << 4;
  int arow = row0 + ar; if (arow >= n) arow = n - 1;
  const float* ap = feat + (size_t)arow * NF + ak;
  int am = ar & 15, art = ar >> 4;
  int s0 = ak >> 5, q0 = (ak >> 3) & 3;
  int s1 = (ak + 8) >> 5, q1 = ((ak + 8) >> 3) & 3;
  int aw0o = (((art * 2 + s0) * 64) + q0 * 16 + am) * 8;
  int aw1o = (((art * 2 + s1) * 64) + q1 * 16 + am) * 8;

  // B direct pointers (one fp32 row per ct fragment)
  const float* bp[4];
#pragma unroll
  for (int ct = 0; ct < 4; ++ct)
    bp[ct] = fc_w + (size_t)(w * 64 + ct * 16 + rr) * NF + kq * 8;

  // prologue: stage k0=0 into buffer 0
  {
    float4 f0 = *(const float4*)(ap);
    float4 f1 = *(const float4*)(ap + 4);
    float4 f2 = *(const float4*)(ap + 8);
    float4 f3 = *(const float4*)(ap + 12);
    uint4 oa = make_uint4(pkbf(f0.x, f0.y), pkbf(f0.z, f0.w),
                          pkbf(f1.x, f1.y), pkbf(f1.z, f1.w));
    uint4 ob = make_uint4(pkbf(f2.x, f2.y), pkbf(f2.z, f2.w),
                          pkbf(f3.x, f3.y), pkbf(f3.z, f3.w));
    *(uint4*)&aF[aw0o] = oa;
    *(uint4*)&aF[aw1o] = ob;
  }

  int buf = 0;
  for (int k0 = 0; k0 < NF; k0 += 64) {
    __syncthreads();
    if (k0 + 64 < NF) {   // prefetch next A chunk into other buffer
      float4 f0 = *(const float4*)(ap + k0 + 64);
      float4 f1 = *(const float4*)(ap + k0 + 68);
      float4 f2 = *(const float4*)(ap + k0 + 72);
      float4 f3 = *(const float4*)(ap + k0 + 76);
      uint4 oa = make_uint4(pkbf(f0.x, f0.y), pkbf(f0.z, f0.w),
                            pkbf(f1.x, f1.y), pkbf(f1.z, f1.w));
      uint4 ob = make_uint4(pkbf(f2.x, f2.y), pkbf(f2.z, f2.w),
                            pkbf(f3.x, f3.y), pkbf(f3.z, f3.w));
      int bo = (buf ^ 1) * 4096;
      *(uint4*)&aF[bo + aw0o] = oa;
      *(uint4*)&aF[bo + aw1o] = ob;
    }
#pragma unroll
    for (int s = 0; s < 2; ++s) {
      short8 af[4], bfr[4];
#pragma unroll
      for (int rt = 0; rt < 4; ++rt)
        af[rt] = *(const short8*)&aF[buf * 4096 + (((rt * 2 + s) * 64) + lane) * 8];
#pragma unroll
      for (int ct = 0; ct < 4; ++ct) {
        float4 bx = *(const float4*)(bp[ct] + k0 + s * 32);
        float4 by = *(const float4*)(bp[ct] + k0 + s * 32 + 4);
        bfr[ct] = cvt8(bx, by);
      }
#pragma unroll
      for (int rt = 0; rt < 4; ++rt)
#pragma unroll
        for (int ct = 0; ct < 4; ++ct)
          acc[rt][ct] = __builtin_amdgcn_mfma_f32_16x16x32_bf16(
              af[rt], bfr[ct], acc[rt][ct], 0, 0, 0);
    }
    buf ^= 1;
  }

  // epilogue: wave w == head w. C/D map: col = lane&15, row = (lane>>4)*4 + r.
  int ln = lane & 15, lq = lane >> 4;
  float al4[4], ar4[4];
#pragma unroll
  for (int ct = 0; ct < 4; ++ct) {
    al4[ct] = attn_l[w * 64 + ct * 16 + ln];
    ar4[ct] = attn_r[w * 64 + ct * 16 + ln];
  }
#pragma unroll
  for (int rt = 0; rt < 4; ++rt) {
#pragma unroll
    for (int r = 0; r < 4; ++r) {
      float pl = 0.f, pr = 0.f;
#pragma unroll
      for (int ct = 0; ct < 4; ++ct) {
        float v = acc[rt][ct][r];
        pl += v * al4[ct]; pr += v * ar4[ct];
      }
#pragma unroll
      for (int off = 1; off <= 8; off <<= 1) {
        pl += __shfl_xor(pl, off);
        pr += __shfl_xor(pr, off);
      }
      int row = row0 + rt * 16 + lq * 4 + r;
      if (row < n) {
        if (ln == 0) { el[row * NH + w] = pl; er[row * NH + w] = pr; }
        unsigned short* fr = ftb + (size_t)row * HD + w * 64 + ln;
#pragma unroll
        for (int ct = 0; ct < 4; ++ct) fr[ct * 16] = f2bf(acc[rt][ct][r]);
      }
    }
  }
}

// K1: het-grid — hist blocks [0,hb) + gemm tiles [0, gridDim-hb)
__global__ __launch_bounds__(256) void hist_gemm_k(
    const int* __restrict__ dst, int* __restrict__ ghist, int e, int epb, int hb,
    const float* __restrict__ feat, const float* __restrict__ fc_w,
    const float* __restrict__ attn_l, const float* __restrict__ attn_r,
    unsigned short* __restrict__ ftb, float* __restrict__ el,
    float* __restrict__ er, int n) {
  __shared__ short aF[2 * 4 * 2 * 64 * 8];   // 16 KB (hist reuses as bins)
  int tid = threadIdx.x;
  if (blockIdx.x < hb) {
    int* bins = (int*)aF;
    int blk = blockIdx.x;
    bins[tid] = 0;
    __syncthreads();
    int e0 = blk * epb, e1 = e0 + epb; if (e1 > e) e1 = e;
    for (int i = e0 + tid; i < e1; i += 256)
      atomicAdd(&bins[dst[i] >> 8], 1);
    __syncthreads();
    ghist[blk * 256 + tid] = bins[tid];   // [blk][bin], coalesced
    return;
  }
  gemm_tile(feat, fc_w, attn_l, attn_r, ftb, el, er, n,
            ((int)blockIdx.x - hb) * 64, tid, aF);
}

// K2: single block, 256 thr (tid = bin). Coalesced column scan over PB blocks.
__global__ __launch_bounds__(256) void scan_k(
    const int* __restrict__ ghist, int* __restrict__ lsg,
    int* __restrict__ bb, int nblk) {
  int tid = threadIdx.x;
  int run = 0;
  int i = 0;
  for (; i + 8 <= nblk; i += 8) {
    int v[8];
#pragma unroll
    for (int j = 0; j < 8; ++j) v[j] = ghist[(i + j) * 256 + tid];
#pragma unroll
    for (int j = 0; j < 8; ++j) { lsg[(i + j) * 256 + tid] = run; run += v[j]; }
  }
  for (; i < nblk; ++i) {
    int v = ghist[i * 256 + tid];
    lsg[i * 256 + tid] = run;
    run += v;
  }
  // block-wide exclusive scan of per-bin totals -> bb
  __shared__ int wt[4];
  int lane = tid & 63, wid = tid >> 6;
  int inc = run;
#pragma unroll
  for (int off = 1; off < 64; off <<= 1) {
    int t = __shfl_up(inc, off);
    if (lane >= off) inc += t;
  }
  if (lane == 63) wt[wid] = inc;
  __syncthreads();
  int base = 0;
  if (wid > 0) base += wt[0];
  if (wid > 1) base += wt[1];
  if (wid > 2) base += wt[2];
  bb[tid] = base + inc - run;
  if (tid == 255) bb[256] = base + inc;
}

// K3: het-grid — scatter blocks [0,sb) + gemm tiles [tile0, ...)
__global__ __launch_bounds__(256) void scat_gemm_k(
    const int* __restrict__ src, const int* __restrict__ dst,
    const int* __restrict__ efeats, const int* __restrict__ lsg,
    const int* __restrict__ bb, int* __restrict__ mid, int e, int epb, int sb,
    const float* __restrict__ feat, const float* __restrict__ fc_w,
    const float* __restrict__ attn_l, const float* __restrict__ attn_r,
    unsigned short* __restrict__ ftb, float* __restrict__ el,
    float* __restrict__ er, int n, int tile0) {
  __shared__ short aF[2 * 4 * 2 * 64 * 8];   // 16 KB (scatter reuses as cursors)
  int tid = threadIdx.x;
  if (blockIdx.x < sb) {
    int* cur = (int*)aF;
    int blk = blockIdx.x;
    cur[tid] = bb[tid] + lsg[blk * 256 + tid];
    __syncthreads();
    int e0 = blk * epb, e1 = e0 + epb; if (e1 > e) e1 = e;
    for (int i = e0 + tid; i < e1; i += 256) {
      int d = dst[i];
      int pos = atomicAdd(&cur[d >> 8], 1);
      mid[pos] = src[i] | ((efeats[i] - 1) << 17) | ((d & 255) << 20);
    }
    return;
  }
  gemm_tile(feat, fc_w, attn_l, attn_r, ftb, el, er, n,
            (tile0 + (int)blockIdx.x - sb) * 64, tid, aF);
}

// K4: per-bucket (256 nodes) LDS counting-group: poffs + dst-grouped pk
__global__ __launch_bounds__(256) void bucket_k(
    const int* __restrict__ mid, const int* __restrict__ bb,
    int* __restrict__ poffs, int* __restrict__ pk, int nN) {
  __shared__ int cnt[256];
  __shared__ int cur[256];
  int tid = threadIdx.x, b = blockIdx.x;
  int bb0 = bb[b];
  int bb1 = bb[b + 1];
  cnt[tid] = 0;
  __syncthreads();
  for (int i = bb0 + tid; i < bb1; i += 256)
    atomicAdd(&cnt[(mid[i] >> 20) & 255], 1);
  __syncthreads();
  if (tid < 64) {
    int carry = 0;
#pragma unroll
    for (int c = 0; c < 4; ++c) {
      int v = cnt[c * 64 + tid];
      int inc = v;
#pragma unroll
      for (int off = 1; off < 64; off <<= 1) {
        int t2 = __shfl_up(inc, off);
        if (tid >= off) inc += t2;
      }
      cur[c * 64 + tid] = inc - v + carry;
      carry += __shfl(inc, 63);
    }
  }
  __syncthreads();
  int node = b * 256 + tid;
  int g = bb0 + cur[tid];
  if (node <= nN) poffs[node] = g;
  cur[tid] = g;
  __syncthreads();
  for (int i = bb0 + tid; i < bb1; i += 256) {
    int v = mid[i];
    int pos = atomicAdd(&cur[(v >> 20) & 255], 1);
    pk[pos] = v & 0xFFFFF;
  }
}

// K5: one wave per dst node; lane owns output cols lane*4..lane*4+3 (head
// hl=lane>>4). Single pass: w=exp(leaky((el+er)*ew)) inline; scale by 1/ss.
__global__ __launch_bounds__(256) void agg3_k(
    const unsigned short* __restrict__ ftb, const int* __restrict__ pk,
    const float* __restrict__ el, const float* __restrict__ er,
    const float* __restrict__ ewt, const int* __restrict__ offs,
    float* __restrict__ out, int n) {
  __shared__ float ew_s[32];
  if (threadIdx.x < 32) {
    float v = ewt[threadIdx.x] * 100.0f;
    ew_s[threadIdx.x] = (v >= 0.f) ? v : 0.01f * v;
  }
  __syncthreads();
  int node = blockIdx.x * 4 + (threadIdx.x >> 6);
  int lane = threadIdx.x & 63;
  if (node >= n) return;
  int start = offs[node];
  int deg = offs[node + 1] - start;
  float o0 = 0.f, o1 = 0.f, o2 = 0.f, o3 = 0.f;
  if (deg > 0) {
    int hl = lane >> 4;
    float er_h = er[(size_t)node * NH + hl];
    const unsigned short* fb = ftb + (size_t)lane * 4;
    const float* elh = el + hl;
    const int* pg = pk + start;
    float ss = 0.f;
    int i = 0;
    for (; i + 8 <= deg; i += 8) {
      int4 pa = *(const int4*)(pg + i);
      int4 pb = *(const int4*)(pg + i + 4);
      int sA = pa.x & 0x1FFFF, tA = pa.x >> 17;
      int sB = pa.y & 0x1FFFF, tB = pa.y >> 17;
      int sC = pa.z & 0x1FFFF, tC = pa.z >> 17;
      int sD = pa.w & 0x1FFFF, tD = pa.w >> 17;
      int sE = pb.x & 0x1FFFF, tE = pb.x >> 17;
      int sF = pb.y & 0x1FFFF, tF = pb.y >> 17;
      int sG = pb.z & 0x1FFFF, tG = pb.z >> 17;
      int sH = pb.w & 0x1FFFF, tH = pb.w >> 17;
      float eA = elh[sA * NH], eB = elh[sB * NH], eC = elh[sC * NH], eD = elh[sD * NH];
      float eE = elh[sE * NH], eF = elh[sF * NH], eG = elh[sG * NH], eH = elh[sH * NH];
      ushort4 fA = *(const ushort4*)(fb + (size_t)sA * HD);
      ushort4 fB = *(const ushort4*)(fb + (size_t)sB * HD);
      ushort4 fC = *(const ushort4*)(fb + (size_t)sC * HD);
      ushort4 fD = *(const ushort4*)(fb + (size_t)sD * HD);
      ushort4 fE = *(const ushort4*)(fb + (size_t)sE * HD);
      ushort4 fF = *(const ushort4*)(fb + (size_t)sF * HD);
      ushort4 fG = *(const ushort4*)(fb + (size_t)sG * HD);
      ushort4 fH = *(const ushort4*)(fb + (size_t)sH * HD);
      float wA = wcalc(eA + er_h, ew_s[tA * NH + hl]);
      float wB = wcalc(eB + er_h, ew_s[tB * NH + hl]);
      float wC = wcalc(eC + er_h, ew_s[tC * NH + hl]);
      float wD = wcalc(eD + er_h, ew_s[tD * NH + hl]);
      float wE = wcalc(eE + er_h, ew_s[tE * NH + hl]);
      float wF = wcalc(eF + er_h, ew_s[tF * NH + hl]);
      float wG = wcalc(eG + er_h, ew_s[tG * NH + hl]);
      float wH = wcalc(eH + er_h, ew_s[tH * NH + hl]);
      ss += ((wA + wB) + (wC + wD)) + ((wE + wF) + (wG + wH));
      o0 = fmaf(wA, bf2f(fA.x), o0); o1 = fmaf(wA, bf2f(fA.y), o1);
      o2 = fmaf(wA, bf2f(fA.z), o2); o3 = fmaf(wA, bf2f(fA.w), o3);
      o0 = fmaf(wB, bf2f(fB.x), o0); o1 = fmaf(wB, bf2f(fB.y), o1);
      o2 = fmaf(wB, bf2f(fB.z), o2); o3 = fmaf(wB, bf2f(fB.w), o3);
      o0 = fmaf(wC, bf2f(fC.x), o0); o1 = fmaf(wC, bf2f(fC.y), o1);
      o2 = fmaf(wC, bf2f(fC.z), o2); o3 = fmaf(wC, bf2f(fC.w), o3);
      o0 = fmaf(wD, bf2f(fD.x), o0); o1 = fmaf(wD, bf2f(fD.y), o1);
      o2 = fmaf(wD, bf2f(fD.z), o2); o3 = fmaf(wD, bf2f(fD.w), o3);
      o0 = fmaf(wE, bf2f(fE.x), o0); o1 = fmaf(wE, bf2f(fE.y), o1);
      o2 = fmaf(wE, bf2f(fE.z), o2); o3 = fmaf(wE, bf2f(fE.w), o3);
      o0 = fmaf(wF, bf2f(fF.x), o0); o1 = fmaf(wF, bf2f(fF.y), o1);
      o2 = fmaf(wF, bf2f(fF.z), o2); o3 = fmaf(wF, bf2f(fF.w), o3);
      o0 = fmaf(wG, bf2f(fG.x), o0); o1 = fmaf(wG, bf2f(fG.y), o1);
      o2 = fmaf(wG, bf2f(fG.z), o2); o3 = fmaf(wG, bf2f(fG.w), o3);
      o0 = fmaf(wH, bf2f(fH.x), o0); o1 = fmaf(wH, bf2f(fH.y), o1);
      o2 = fmaf(wH, bf2f(fH.z), o2); o3 = fmaf(wH, bf2f(fH.w), o3);
    }
    for (; i < deg; ++i) {
      int pv = pg[i];
      int sA = pv & 0x1FFFF, tA = pv >> 17;
      float eA = elh[sA * NH];
      ushort4 fA = *(const ushort4*)(fb + (size_t)sA * HD);
      float wA = wcalc(eA + er_h, ew_s[tA * NH + hl]);
      ss += wA;
      o0 = fmaf(wA, bf2f(fA.x), o0); o1 = fmaf(wA, bf2f(fA.y), o1);
      o2 = fmaf(wA, bf2f(fA.z), o2); o3 = fmaf(wA, bf2f(fA.w), o3);
    }
    float rs = 1.0f / ss;
    o0 *= rs; o1 *= rs; o2 *= rs; o3 *= rs;
  }
  *(float4*)(out + (size_t)node * HD + lane * 4) = make_float4(o0, o1, o2, o3);
}

extern "C" void kernel_launch(void* const* d_in, const int* in_sizes, int n_in,
                              void* d_out, int out_size, void* d_ws, size_t ws_size,
                              hipStream_t stream) {
  const float* feat   = (const float*)d_in[0];
  const int*   src    = (const int*)d_in[1];
  const int*   dst    = (const int*)d_in[2];
  const int*   efeats = (const int*)d_in[3];
  const float* fc_w   = (const float*)d_in[4];
  const float* attn_l = (const float*)d_in[5];
  const float* attn_r = (const float*)d_in[6];
  const float* ewt    = (const float*)d_in[7];
  float* out = (float*)d_out;

  int N = in_sizes[0] / NF;   // 50000
  int E = in_sizes[1];        // 800000

  char* ws = (char*)d_ws;
  size_t off = 0;
  unsigned short* ftb = (unsigned short*)(ws + off); off += (size_t)N * HD * 2;   // 25.6 MB
  float* el  = (float*)(ws + off);  off += (size_t)N * NH * 4;
  float* er  = (float*)(ws + off);  off += (size_t)N * NH * 4;
  int* poffs = (int*)(ws + off);    off += ((size_t)N + 16) * 4;
  int* ghist = (int*)(ws + off);    off += (size_t)PB * 256 * 4;                  // 256 KB
  int* lsg   = (int*)(ws + off);    off += (size_t)PB * 256 * 4;                  // 256 KB
  int* bb    = (int*)(ws + off);    off += 260 * 4;
  int* mid   = (int*)(ws + off);    off += (size_t)E * 4;                          // 3.2 MB
  int* pk    = (int*)(ws + off);    off += (size_t)E * 4;                          // 3.2 MB

  int gb = (N + 63) / 64;            // 782 GEMM tiles
  int g1 = 430;                      // tiles overlapped with hist (lighter)
  int g2 = gb - g1;                  // 352 tiles overlapped with scatter
  int epb = (E + PB - 1) / PB;       // 3125 edges per partition block
  int nbuck = (N + 255) >> 8;        // 196 buckets

  hist_gemm_k<<<PB + g1, 256, 0, stream>>>(dst, ghist, E, epb, PB,
                                           feat, fc_w, attn_l, attn_r,
                                           ftb, el, er, N);
  scan_k<<<1, 256, 0, stream>>>(ghist, lsg, bb, PB);
  scat_gemm_k<<<PB + g2, 256, 0, stream>>>(src, dst, efeats, lsg, bb, mid,
                                           E, epb, PB,
                                           feat, fc_w, attn_l, attn_r,
                                           ftb, el, er, N, g1);
  bucket_k<<<nbuck, 256, 0, stream>>>(mid, bb, poffs, pk, N);
  agg3_k<<<(N + 3) / 4, 256, 0, stream>>>(ftb, pk, el, er, ewt, poffs, out, N);
}